// Round 9
// baseline (237.078 us; speedup 1.0000x reference)
//
#include <hip/hip_runtime.h>
#include <hip/hip_bf16.h>

typedef unsigned short u16;
typedef __bf16 bf16x8 __attribute__((ext_vector_type(8)));
typedef float f32x4 __attribute__((ext_vector_type(4)));

#define HIDDEN 1024
#define NH 16
#define HD 64
#define BATCH 2
#define SEQ 2048
#define MTOT (BATCH*SEQ)   // 4096
#define TSPLIT 2           // t-dimension split of attention
#define CEXP 0.18033688f   // 0.125 * log2(e), folded into Q at projection time

__device__ __forceinline__ u16 f2bf(float f) {
  union { float f; unsigned u; } v; v.f = f;
  unsigned u = v.u;
  return (u16)((u + 0x7fffu + ((u >> 16) & 1u)) >> 16);   // RNE
}

__device__ __forceinline__ unsigned pack2bf(float a, float b) {
  __hip_bfloat162 h = __float22bfloat162_rn(make_float2(a, b));
  unsigned u; __builtin_memcpy(&u, &h, 4); return u;
}

__device__ __forceinline__ void gload16(const u16* g, u16* l) {
  __builtin_amdgcn_global_load_lds((const __attribute__((address_space(1))) unsigned int*)g,
                                   (__attribute__((address_space(3))) unsigned int*)l, 16, 0, 0);
}

// ---------------- prep: x fp32 -> bf16 ----------------
__global__ __launch_bounds__(256) void convert_x_kernel(const float* __restrict__ x,
                                                        u16* __restrict__ xb) {
  size_t i = ((size_t)blockIdx.x * 256 + threadIdx.x) * 4;
  float4 v = *(const float4*)(x + i);
  uint2 p;
  p.x = pack2bf(v.x, v.y);
  p.y = pack2bf(v.z, v.w);
  *(uint2*)(xb + i) = p;
}

// ---------------- prep: W (k,n) fp32 -> Wt (n,k) bf16 ----------------
__global__ __launch_bounds__(256) void transpose_w_kernel(const float* __restrict__ w0, const float* __restrict__ w1,
                                                          const float* __restrict__ w2, const float* __restrict__ w3,
                                                          u16* __restrict__ dqkv, u16* __restrict__ dwo) {
  __shared__ float t[32][33];
  int z = blockIdx.z;
  const float* src = (z==0) ? w0 : (z==1) ? w1 : (z==2) ? w2 : w3;
  u16* dst = (z < 3) ? (dqkv + (size_t)z * HIDDEN * HIDDEN) : dwo;
  int kb = blockIdx.x * 32, nb = blockIdx.y * 32;
  int tx = threadIdx.x & 31, ty = threadIdx.x >> 5;
  for (int r = ty; r < 32; r += 8) t[r][tx] = src[(size_t)(kb + r) * HIDDEN + nb + tx];
  __syncthreads();
  for (int r = ty; r < 32; r += 8) dst[(size_t)(nb + r) * HIDDEN + kb + tx] = f2bf(t[tx][r]);
}

// ---------------- prep: V (t,d) -> Vt (d,t) per head ----------------
__global__ __launch_bounds__(256) void transpose_v_kernel(const u16* __restrict__ qkv,
                                                          u16* __restrict__ vt) {
  __shared__ u16 t[32][33];
  int bh = blockIdx.z; int b = bh >> 4, h = bh & 15;
  int t0 = blockIdx.x * 32, d0 = blockIdx.y * 32;
  int tx = threadIdx.x & 31, ty = threadIdx.x >> 5;
  for (int r = ty; r < 32; r += 8)
    t[r][tx] = qkv[(size_t)(b*SEQ + t0 + r) * (3*HIDDEN) + 2*HIDDEN + h*HD + d0 + tx];
  __syncthreads();
  for (int r = ty; r < 32; r += 8)
    vt[(size_t)(bh*HD + d0 + r) * SEQ + t0 + tx] = t[tx][r];
}

// ---------------- bf16 GEMM: C[m,n] = sum_k A[m,k]*Bt[n,k] + bias ----------------
// MT x 128 tile (MT=128 or 64), BK=32, global_load_lds width-16 staging.
// MODE 0: fp32 out = acc + b0[n]                       (output projection)
// MODE 1: bf16 out, 3 segments: Q (scaled by CEXP), K, V -> qkvb
template<int MODE, int MT>
__global__ __launch_bounds__(256) void gemm_bt(const u16* __restrict__ A, const u16* __restrict__ Bt,
                                               const float* __restrict__ b0, const float* __restrict__ b1,
                                               const float* __restrict__ b2,
                                               u16* __restrict__ Cq, float* __restrict__ Cf,
                                               int M, int N, int K) {
  constexpr int MF = MT / 32;           // m-frags per wave: 4 (MT=128) or 2 (MT=64)
  __shared__ u16 As[MT*32];
  __shared__ u16 Bs[128*32];
  const int tid = threadIdx.x, lane = tid & 63, wv = tid >> 6;
  const int m0 = blockIdx.x * MT, n0 = blockIdx.y * 128;
  const int wm = (wv >> 1) * (MT/2), wn = (wv & 1) * 64;
  const int col = lane & 15, quad = lane >> 4;
  const int lr = lane >> 2, lk = (lane & 3) * 8;
  f32x4 acc[MF][4] = {};
  for (int k0 = 0; k0 < K; k0 += 32) {
    if constexpr (MT == 128) {
      gload16(&A[(size_t)(m0 + wv*32      + lr)*K + k0 + lk], &As[wv*1024]);
      gload16(&A[(size_t)(m0 + wv*32 + 16 + lr)*K + k0 + lk], &As[wv*1024 + 512]);
    } else {
      gload16(&A[(size_t)(m0 + wv*16      + lr)*K + k0 + lk], &As[wv*512]);
    }
    gload16(&Bt[(size_t)(n0 + wv*32      + lr)*K + k0 + lk], &Bs[wv*1024]);
    gload16(&Bt[(size_t)(n0 + wv*32 + 16 + lr)*K + k0 + lk], &Bs[wv*1024 + 512]);
    __syncthreads();
    bf16x8 af[MF], bfr[4];
    #pragma unroll
    for (int i = 0; i < MF; i++) af[i]  = *(const bf16x8*)&As[(wm + i*16 + col)*32 + quad*8];
    #pragma unroll
    for (int i = 0; i < 4; i++)  bfr[i] = *(const bf16x8*)&Bs[(wn + i*16 + col)*32 + quad*8];
    #pragma unroll
    for (int mi = 0; mi < MF; mi++)
      #pragma unroll
      for (int ni = 0; ni < 4; ni++)
        acc[mi][ni] = __builtin_amdgcn_mfma_f32_16x16x32_bf16(af[mi], bfr[ni], acc[mi][ni], 0, 0, 0);
    __syncthreads();
  }
  if constexpr (MODE == 0) {
    #pragma unroll
    for (int mi = 0; mi < MF; mi++)
      #pragma unroll
      for (int ni = 0; ni < 4; ni++) {
        int n = n0 + wn + ni*16 + col;
        float bias = b0[n];
        #pragma unroll
        for (int r = 0; r < 4; r++) {
          int m = m0 + wm + mi*16 + quad*4 + r;   // C/D: row = quad*4+reg, col = lane&15
          Cf[(size_t)m*N + n] = acc[mi][ni][r] + bias;
        }
      }
  } else {
    const int seg = n0 >> 10;   // 0=Q, 1=K, 2=V
    const float* bias = (seg == 0) ? b0 : (seg == 1) ? b1 : b2;
    const float scl = (seg == 0) ? CEXP : 1.0f;
    #pragma unroll
    for (int mi = 0; mi < MF; mi++)
      #pragma unroll
      for (int ni = 0; ni < 4; ni++) {
        int n = n0 + wn + ni*16 + col;
        float bv = bias[n & (HIDDEN-1)];
        #pragma unroll
        for (int r = 0; r < 4; r++) {
          int m = m0 + wm + mi*16 + quad*4 + r;
          Cq[(size_t)m*N + n] = f2bf((acc[mi][ni][r] + bv) * scl);
        }
      }
  }
}

// ---------------- flash attention v5: t-split partials + dbuf DMA-staged K/V ----------------
// grid (qt=16, bh=32, ts=2): block handles 128 q x 1024 t of one (b,h), emits UNNORMALIZED
// fp32 partial O^T and partial row sums (no-max softmax is additive over t -> exact).
// Staging/compute structure identical to R7 (dbuf global_load_lds + XOR chunk swizzle, one
// barrier per 64-t tile). Q pre-scaled by CEXP; row sums via ones-MFMA.
__global__ __launch_bounds__(256) void attn_kernel(const u16* __restrict__ qkv,
                                                   const u16* __restrict__ vt,
                                                   float* __restrict__ pO,
                                                   float* __restrict__ pR) {
  __shared__ u16 Ks[2*64*64];    // [buf][t][d-chunk-swizzled], 8KB/buf
  __shared__ u16 Vs[2*64*64];    // [buf][d][t-chunk-swizzled]
  __shared__ u16 Ps[4][32*72];   // per-wave P^T [q(32)][t(64)], stride 72 (regular ds ops)
  const int tid = threadIdx.x, lane = tid & 63, wv = tid >> 6;
  const int qt = blockIdx.x, bh = blockIdx.y, ts = blockIdx.z;
  const int b = bh >> 4, h = bh & 15;
  const int col = lane & 15, quad = lane >> 4;
  const int tbase = ts * (SEQ / TSPLIT);

  // Q as B-fragments (n=lane&15, k=quad*8+j): 2 q-subtiles x 2 k-halves
  bf16x8 qf[2][2];
  #pragma unroll
  for (int nq = 0; nq < 2; nq++) {
    const u16* qrow = qkv + (size_t)(b*SEQ + qt*128 + wv*32 + nq*16 + col) * (3*HIDDEN) + h*HD + quad*8;
    qf[nq][0] = *(const bf16x8*)(qrow);
    qf[nq][1] = *(const bf16x8*)(qrow + 32);
  }
  bf16x8 ones;
  #pragma unroll
  for (int i = 0; i < 8; i++) ones[i] = (__bf16)1.0f;

  f32x4 o[2][4] = {};      // O^T acc: [nq][mi], col=q, row=d
  f32x4 rsacc[2] = {};     // row-sum acc via ones-MFMA

  // staging geometry: thread covers rows r0=tid>>3 (0..31) and r0+32; fetches global chunk
  // cg = (tid&7) ^ (r&7); DMA writes LDS at tid*16B (lane-contiguous, m104 constraint).
  const int r0 = tid >> 3;
  const int cg = ((tid & 7) ^ (r0 & 7)) * 8;
  const u16* gK = qkv + (size_t)b*SEQ*(3*HIDDEN) + HIDDEN + (size_t)h*HD;   // K[t][d], row 3072
  const u16* gV = vt + (size_t)bh*HD*SEQ;                                    // Vt[d][t], row 2048

  // swizzled read chunk offsets for this lane (kk=0,1): ((kk*4+quad)^(col&7))*8
  const int ck0 = ((quad)     ^ (col & 7)) * 8;
  const int ck1 = ((4 + quad) ^ (col & 7)) * 8;

  // prologue: stage tile 0 into buf 0
  gload16(&gK[(size_t)(tbase + r0     )*(3*HIDDEN) + cg], &Ks[wv*512]);
  gload16(&gK[(size_t)(tbase + r0 + 32)*(3*HIDDEN) + cg], &Ks[2048 + wv*512]);
  gload16(&gV[(size_t)(r0     )*SEQ + tbase + cg],        &Vs[wv*512]);
  gload16(&gV[(size_t)(r0 + 32)*SEQ + tbase + cg],        &Vs[2048 + wv*512]);

  constexpr int NIT = SEQ / TSPLIT / 64;
  for (int it = 0; it < NIT; ++it) {
    const int cur = (it & 1) * 4096;
    __syncthreads();   // drains vmcnt -> tile it staged; all waves done reading buf[cur^1]
    if (it + 1 < NIT) {   // async-stage tile it+1 into the other buffer; flies during compute
      const int nxt = ((it + 1) & 1) * 4096;
      const int t0 = tbase + (it + 1) * 64;
      gload16(&gK[(size_t)(t0 + r0     )*(3*HIDDEN) + cg], &Ks[nxt + wv*512]);
      gload16(&gK[(size_t)(t0 + r0 + 32)*(3*HIDDEN) + cg], &Ks[nxt + 2048 + wv*512]);
      gload16(&gV[(size_t)(r0     )*SEQ + t0 + cg],        &Vs[nxt + wv*512]);
      gload16(&gV[(size_t)(r0 + 32)*SEQ + t0 + cg],        &Vs[nxt + 2048 + wv*512]);
    }

    // S^T = K Q^T: A=K (m=t), B=Q (n=q). s[nq][nt]: lane q=col, t=nt*16+quad*4+r.
    f32x4 s[2][4] = {};
    #pragma unroll
    for (int kk = 0; kk < 2; kk++)
      #pragma unroll
      for (int nt = 0; nt < 4; nt++) {
        bf16x8 kf = *(const bf16x8*)&Ks[cur + (nt*16 + col)*64 + (kk ? ck1 : ck0)];
        #pragma unroll
        for (int nq = 0; nq < 2; nq++)
          s[nq][nt] = __builtin_amdgcn_mfma_f32_16x16x32_bf16(kf, qf[nq][kk], s[nq][nt], 0, 0, 0);
      }

    // p = exp2(s) (Q pre-scaled); packed P^T write
    #pragma unroll
    for (int nq = 0; nq < 2; nq++)
      #pragma unroll
      for (int nt = 0; nt < 4; nt++) {
        float p0 = __builtin_exp2f(s[nq][nt][0]);
        float p1 = __builtin_exp2f(s[nq][nt][1]);
        float p2 = __builtin_exp2f(s[nq][nt][2]);
        float p3 = __builtin_exp2f(s[nq][nt][3]);
        uint2 w2; w2.x = pack2bf(p0, p1); w2.y = pack2bf(p2, p3);
        *(uint2*)&Ps[wv][(nq*16 + col)*72 + nt*16 + quad*4] = w2;   // P^T[q][t]
      }
    asm volatile("s_waitcnt lgkmcnt(0)" ::: "memory");  // same-wave P write->read ordering

    // O^T += V^T P^T; row sums += ones * P^T
    #pragma unroll
    for (int kk = 0; kk < 2; kk++) {
      bf16x8 pf[2];
      #pragma unroll
      for (int nq = 0; nq < 2; nq++)
        pf[nq] = *(const bf16x8*)&Ps[wv][(nq*16 + col)*72 + kk*32 + quad*8];
      #pragma unroll
      for (int mi = 0; mi < 4; mi++) {
        bf16x8 vf = *(const bf16x8*)&Vs[cur + (mi*16 + col)*64 + (kk ? ck1 : ck0)];
        #pragma unroll
        for (int nq = 0; nq < 2; nq++)
          o[nq][mi] = __builtin_amdgcn_mfma_f32_16x16x32_bf16(vf, pf[nq], o[nq][mi], 0, 0, 0);
      }
      #pragma unroll
      for (int nq = 0; nq < 2; nq++)
        rsacc[nq] = __builtin_amdgcn_mfma_f32_16x16x32_bf16(ones, pf[nq], rsacc[nq], 0, 0, 0);
    }
  }

  // store fp32 partials: pO[ts][qg][h*64+d] (float4, L2-merges to contiguous rows), pR[ts][bh][q]
  #pragma unroll
  for (int nq = 0; nq < 2; nq++) {
    const int qg = b*SEQ + qt*128 + wv*32 + nq*16 + col;
    float* pop = pO + (size_t)ts*MTOT*HIDDEN + (size_t)qg*HIDDEN + h*HD;
    #pragma unroll
    for (int mi = 0; mi < 4; mi++)
      *(f32x4*)&pop[mi*16 + quad*4] = o[nq][mi];
    if (quad == 0)
      pR[(size_t)ts*(BATCH*NH*SEQ) + (size_t)bh*SEQ + (qt*128 + wv*32 + nq*16 + col)] = rsacc[nq][0];
  }
}

// ---------------- combine: sum t-split partials, normalize, emit bf16 ----------------
__global__ __launch_bounds__(256) void combine_kernel(const float* __restrict__ pO,
                                                      const float* __restrict__ pR,
                                                      u16* __restrict__ ao) {
  const int qg = blockIdx.x, t = threadIdx.x;
  const int d0 = t * 4;                       // 4 d per thread
  const int bh = (qg >> 11) * NH + (d0 >> 6); // b*16 + h
  const int q  = qg & (SEQ - 1);
  float4 a = *(const float4*)&pO[(size_t)qg*HIDDEN + d0];
  float4 c = *(const float4*)&pO[(size_t)MTOT*HIDDEN + (size_t)qg*HIDDEN + d0];
  float rs = pR[(size_t)bh*SEQ + q] + pR[(size_t)(BATCH*NH*SEQ) + (size_t)bh*SEQ + q];
  float inv = 1.0f / rs;
  uint2 w2;
  w2.x = pack2bf((a.x + c.x) * inv, (a.y + c.y) * inv);
  w2.y = pack2bf((a.z + c.z) * inv, (a.w + c.w) * inv);
  *(uint2*)&ao[(size_t)qg*HIDDEN + d0] = w2;
}

extern "C" void kernel_launch(void* const* d_in, const int* in_sizes, int n_in,
                              void* d_out, int out_size, void* d_ws, size_t ws_size,
                              hipStream_t stream) {
  const float* x  = (const float*)d_in[0];
  const float* Wq = (const float*)d_in[1];
  const float* bq = (const float*)d_in[2];
  const float* Wk = (const float*)d_in[3];
  const float* bk = (const float*)d_in[4];
  const float* Wv = (const float*)d_in[5];
  const float* bv = (const float*)d_in[6];
  const float* Wo = (const float*)d_in[7];
  const float* bo = (const float*)d_in[8];
  float* out = (float*)d_out;

  char* w = (char*)d_ws;
  u16*   xb    = (u16*)w;   w += (size_t)MTOT*HIDDEN*2;          // 8 MB
  u16*   wtqkv = (u16*)w;   w += (size_t)3*HIDDEN*HIDDEN*2;      // 6 MB
  u16*   wto   = (u16*)w;   w += (size_t)HIDDEN*HIDDEN*2;        // 2 MB
  u16*   qkvb  = (u16*)w;   w += (size_t)MTOT*3*HIDDEN*2;        // 24 MB
  u16*   vtb   = (u16*)w;   w += (size_t)BATCH*NH*HD*SEQ*2;      // 8 MB
  u16*   aob   = (u16*)w;   w += (size_t)MTOT*HIDDEN*2;          // 8 MB
  float* pO    = (float*)w; w += (size_t)TSPLIT*MTOT*HIDDEN*4;   // 32 MB
  float* pR    = (float*)w; w += (size_t)TSPLIT*BATCH*NH*SEQ*4;  // 0.5 MB

  convert_x_kernel<<<(MTOT*HIDDEN)/1024, 256, 0, stream>>>(x, xb);
  transpose_w_kernel<<<dim3(32, 32, 4), 256, 0, stream>>>(Wq, Wk, Wv, Wo, wtqkv, wto);
  gemm_bt<1,128><<<dim3(32, 24), 256, 0, stream>>>(xb, wtqkv, bq, bk, bv, qkvb, nullptr, MTOT, 3*HIDDEN, HIDDEN);
  transpose_v_kernel<<<dim3(SEQ/32, 2, BATCH*NH), 256, 0, stream>>>(qkvb, vtb);
  attn_kernel<<<dim3(SEQ/128, BATCH*NH, TSPLIT), 256, 0, stream>>>(qkvb, vtb, pO, pR);
  combine_kernel<<<MTOT, 256, 0, stream>>>(pO, pR, aob);
  gemm_bt<0,64><<<dim3(64, 8), 256, 0, stream>>>(aob, wto, bo, nullptr, nullptr, nullptr, out, MTOT, HIDDEN, HIDDEN);
}

// Round 10
// 231.403 us; speedup vs baseline: 1.0245x; 1.0245x over previous
//
#include <hip/hip_runtime.h>
#include <hip/hip_bf16.h>

typedef unsigned short u16;
typedef __bf16 bf16x8 __attribute__((ext_vector_type(8)));
typedef short s16x4 __attribute__((ext_vector_type(4)));
typedef float f32x4 __attribute__((ext_vector_type(4)));

#define HIDDEN 1024
#define NH 16
#define HD 64
#define BATCH 2
#define SEQ 2048
#define MTOT (BATCH*SEQ)   // 4096
#define CEXP 0.18033688f   // 0.125 * log2(e), folded into Q at projection time

__device__ __forceinline__ u16 f2bf(float f) {
  union { float f; unsigned u; } v; v.f = f;
  unsigned u = v.u;
  return (u16)((u + 0x7fffu + ((u >> 16) & 1u)) >> 16);   // RNE
}

__device__ __forceinline__ unsigned pack2bf(float a, float b) {
  __hip_bfloat162 h = __float22bfloat162_rn(make_float2(a, b));
  unsigned u; __builtin_memcpy(&u, &h, 4); return u;
}

__device__ __forceinline__ void gload16(const u16* g, u16* l) {
  __builtin_amdgcn_global_load_lds((const __attribute__((address_space(1))) unsigned int*)g,
                                   (__attribute__((address_space(3))) unsigned int*)l, 16, 0, 0);
}

// 16x16x16 bf16 MFMA (K=16): B-operand k=quad*4+j matches the QK C-layout row t=quad*4+r,
// so P fragments come straight from registers (no LDS round-trip).
__device__ __forceinline__ f32x4 mfma16(s16x4 a, s16x4 b, f32x4 c) {
#if __has_builtin(__builtin_amdgcn_mfma_f32_16x16x16bf16_1k)
  return __builtin_amdgcn_mfma_f32_16x16x16bf16_1k(a, b, c, 0, 0, 0);
#else
  asm volatile("v_mfma_f32_16x16x16_bf16 %0, %1, %2, %0" : "+v"(c) : "v"(a), "v"(b));
  return c;
#endif
}

// ---------------- prep: x fp32 -> bf16 ----------------
__global__ __launch_bounds__(256) void convert_x_kernel(const float* __restrict__ x,
                                                        u16* __restrict__ xb) {
  size_t i = ((size_t)blockIdx.x * 256 + threadIdx.x) * 4;
  float4 v = *(const float4*)(x + i);
  uint2 p;
  p.x = pack2bf(v.x, v.y);
  p.y = pack2bf(v.z, v.w);
  *(uint2*)(xb + i) = p;
}

// ---------------- prep: W (k,n) fp32 -> Wt (n,k) bf16 ----------------
__global__ __launch_bounds__(256) void transpose_w_kernel(const float* __restrict__ w0, const float* __restrict__ w1,
                                                          const float* __restrict__ w2, const float* __restrict__ w3,
                                                          u16* __restrict__ dqkv, u16* __restrict__ dwo) {
  __shared__ float t[32][33];
  int z = blockIdx.z;
  const float* src = (z==0) ? w0 : (z==1) ? w1 : (z==2) ? w2 : w3;
  u16* dst = (z < 3) ? (dqkv + (size_t)z * HIDDEN * HIDDEN) : dwo;
  int kb = blockIdx.x * 32, nb = blockIdx.y * 32;
  int tx = threadIdx.x & 31, ty = threadIdx.x >> 5;
  for (int r = ty; r < 32; r += 8) t[r][tx] = src[(size_t)(kb + r) * HIDDEN + nb + tx];
  __syncthreads();
  for (int r = ty; r < 32; r += 8) dst[(size_t)(nb + r) * HIDDEN + kb + tx] = f2bf(t[tx][r]);
}

// ---------------- prep: V (t,d) -> Vt (d,t) per head ----------------
__global__ __launch_bounds__(256) void transpose_v_kernel(const u16* __restrict__ qkv,
                                                          u16* __restrict__ vt) {
  __shared__ u16 t[32][33];
  int bh = blockIdx.z; int b = bh >> 4, h = bh & 15;
  int t0 = blockIdx.x * 32, d0 = blockIdx.y * 32;
  int tx = threadIdx.x & 31, ty = threadIdx.x >> 5;
  for (int r = ty; r < 32; r += 8)
    t[r][tx] = qkv[(size_t)(b*SEQ + t0 + r) * (3*HIDDEN) + 2*HIDDEN + h*HD + d0 + tx];
  __syncthreads();
  for (int r = ty; r < 32; r += 8)
    vt[(size_t)(bh*HD + d0 + r) * SEQ + t0 + tx] = t[tx][r];
}

// ---------------- bf16 GEMM: C[m,n] = sum_k A[m,k]*Bt[n,k] + bias ----------------
// MT x 128 tile (MT=128 or 64), BK=32, global_load_lds width-16 staging.
// MODE 0: fp32 out = acc + b0[n]                       (output projection)
// MODE 1: bf16 out, 3 segments: Q (scaled by CEXP), K, V -> qkvb
template<int MODE, int MT>
__global__ __launch_bounds__(256) void gemm_bt(const u16* __restrict__ A, const u16* __restrict__ Bt,
                                               const float* __restrict__ b0, const float* __restrict__ b1,
                                               const float* __restrict__ b2,
                                               u16* __restrict__ Cq, float* __restrict__ Cf,
                                               int M, int N, int K) {
  constexpr int MF = MT / 32;           // m-frags per wave: 4 (MT=128) or 2 (MT=64)
  __shared__ u16 As[MT*32];
  __shared__ u16 Bs[128*32];
  const int tid = threadIdx.x, lane = tid & 63, wv = tid >> 6;
  const int m0 = blockIdx.x * MT, n0 = blockIdx.y * 128;
  const int wm = (wv >> 1) * (MT/2), wn = (wv & 1) * 64;
  const int col = lane & 15, quad = lane >> 4;
  const int lr = lane >> 2, lk = (lane & 3) * 8;
  f32x4 acc[MF][4] = {};
  for (int k0 = 0; k0 < K; k0 += 32) {
    if constexpr (MT == 128) {
      gload16(&A[(size_t)(m0 + wv*32      + lr)*K + k0 + lk], &As[wv*1024]);
      gload16(&A[(size_t)(m0 + wv*32 + 16 + lr)*K + k0 + lk], &As[wv*1024 + 512]);
    } else {
      gload16(&A[(size_t)(m0 + wv*16      + lr)*K + k0 + lk], &As[wv*512]);
    }
    gload16(&Bt[(size_t)(n0 + wv*32      + lr)*K + k0 + lk], &Bs[wv*1024]);
    gload16(&Bt[(size_t)(n0 + wv*32 + 16 + lr)*K + k0 + lk], &Bs[wv*1024 + 512]);
    __syncthreads();
    bf16x8 af[MF], bfr[4];
    #pragma unroll
    for (int i = 0; i < MF; i++) af[i]  = *(const bf16x8*)&As[(wm + i*16 + col)*32 + quad*8];
    #pragma unroll
    for (int i = 0; i < 4; i++)  bfr[i] = *(const bf16x8*)&Bs[(wn + i*16 + col)*32 + quad*8];
    #pragma unroll
    for (int mi = 0; mi < MF; mi++)
      #pragma unroll
      for (int ni = 0; ni < 4; ni++)
        acc[mi][ni] = __builtin_amdgcn_mfma_f32_16x16x32_bf16(af[mi], bfr[ni], acc[mi][ni], 0, 0, 0);
    __syncthreads();
  }
  if constexpr (MODE == 0) {
    #pragma unroll
    for (int mi = 0; mi < MF; mi++)
      #pragma unroll
      for (int ni = 0; ni < 4; ni++) {
        int n = n0 + wn + ni*16 + col;
        float bias = b0[n];
        #pragma unroll
        for (int r = 0; r < 4; r++) {
          int m = m0 + wm + mi*16 + quad*4 + r;   // C/D: row = quad*4+reg, col = lane&15
          Cf[(size_t)m*N + n] = acc[mi][ni][r] + bias;
        }
      }
  } else {
    const int seg = n0 >> 10;   // 0=Q, 1=K, 2=V
    const float* bias = (seg == 0) ? b0 : (seg == 1) ? b1 : b2;
    const float scl = (seg == 0) ? CEXP : 1.0f;
    #pragma unroll
    for (int mi = 0; mi < MF; mi++)
      #pragma unroll
      for (int ni = 0; ni < 4; ni++) {
        int n = n0 + wn + ni*16 + col;
        float bv = bias[n & (HIDDEN-1)];
        #pragma unroll
        for (int r = 0; r < 4; r++) {
          int m = m0 + wm + mi*16 + quad*4 + r;
          Cq[(size_t)m*N + n] = f2bf((acc[mi][ni][r] + bv) * scl);
        }
      }
  }
}

// ---------------- flash attention v6: P stays in registers (16x16x16 PV) ----------------
// block: 128 q of one (b,h); 4 waves x 32 q. Dbuf DMA-staged K/V (XOR chunk swizzle), one
// barrier per 64-t tile. QK via 16x16x32; its C-layout rows (t=quad*4+r) ARE the 16x16x16
// B-fragment k-layout (k=quad*4+j), so exp2'd P packs directly into PV MFMA operands —
// no P LDS round-trip, no mid-iter drain. Row sums via ones-A 16x16x16. LDS = 32 KB.
__global__ __launch_bounds__(256) void attn_kernel(const u16* __restrict__ qkv,
                                                   const u16* __restrict__ vt,
                                                   u16* __restrict__ ao) {
  __shared__ u16 Ks[2*64*64];    // [buf][t][d-chunk-swizzled], 8KB/buf
  __shared__ u16 Vs[2*64*64];    // [buf][d][t-chunk-swizzled]
  const int tid = threadIdx.x, lane = tid & 63, wv = tid >> 6;
  const int qt = blockIdx.x, bh = blockIdx.y;
  const int b = bh >> 4, h = bh & 15;
  const int col = lane & 15, quad = lane >> 4;

  // Q as B-fragments for 16x16x32 (n=lane&15, k=quad*8+j): 2 q-subtiles x 2 k-halves
  bf16x8 qf[2][2];
  #pragma unroll
  for (int nq = 0; nq < 2; nq++) {
    const u16* qrow = qkv + (size_t)(b*SEQ + qt*128 + wv*32 + nq*16 + col) * (3*HIDDEN) + h*HD + quad*8;
    qf[nq][0] = *(const bf16x8*)(qrow);
    qf[nq][1] = *(const bf16x8*)(qrow + 32);
  }
  s16x4 ones16;
  #pragma unroll
  for (int i = 0; i < 4; i++) ones16[i] = (short)0x3F80;   // bf16 1.0

  f32x4 o[2][4] = {};      // O^T acc: [nq][mi], col=q, row=d
  f32x4 rsacc[2] = {};     // row-sum acc via ones-MFMA

  // staging geometry: thread covers rows r0=tid>>3 (0..31) and r0+32; fetches global chunk
  // cg = (tid&7) ^ (r&7); DMA writes LDS at tid*16B (lane-contiguous, m104 constraint).
  const int r0 = tid >> 3;
  const int cg = ((tid & 7) ^ (r0 & 7)) * 8;
  const u16* gK = qkv + (size_t)b*SEQ*(3*HIDDEN) + HIDDEN + (size_t)h*HD;   // K[t][d], row 3072
  const u16* gV = vt + (size_t)bh*HD*SEQ;                                    // Vt[d][t], row 2048

  // K b128 read chunk offsets (kk=0,1): ((kk*4+quad)^(col&7))*8 elements
  const int ck0 = ((quad)     ^ (col & 7)) * 8;
  const int ck1 = ((4 + quad) ^ (col & 7)) * 8;
  // V b64 read offsets per nt: chunk (nt*2+(quad>>1))^(col&7), half (quad&1)
  int cv[4];
  #pragma unroll
  for (int nt = 0; nt < 4; nt++)
    cv[nt] = ((nt*2 + (quad >> 1)) ^ (col & 7)) * 8 + (quad & 1) * 4;

  // prologue: stage tile 0 into buf 0
  gload16(&gK[(size_t)(r0     )*(3*HIDDEN) + cg], &Ks[wv*512]);
  gload16(&gK[(size_t)(r0 + 32)*(3*HIDDEN) + cg], &Ks[2048 + wv*512]);
  gload16(&gV[(size_t)(r0     )*SEQ + cg],        &Vs[wv*512]);
  gload16(&gV[(size_t)(r0 + 32)*SEQ + cg],        &Vs[2048 + wv*512]);

  constexpr int NIT = SEQ/64;
  for (int it = 0; it < NIT; ++it) {
    const int cur = (it & 1) * 4096;
    __syncthreads();   // drains vmcnt -> tile it staged; all waves done reading buf[cur^1]
    if (it + 1 < NIT) {   // async-stage tile it+1 into the other buffer; flies during compute
      const int nxt = ((it + 1) & 1) * 4096;
      const int t0 = (it + 1) * 64;
      gload16(&gK[(size_t)(t0 + r0     )*(3*HIDDEN) + cg], &Ks[nxt + wv*512]);
      gload16(&gK[(size_t)(t0 + r0 + 32)*(3*HIDDEN) + cg], &Ks[nxt + 2048 + wv*512]);
      gload16(&gV[(size_t)(r0     )*SEQ + t0 + cg],        &Vs[nxt + wv*512]);
      gload16(&gV[(size_t)(r0 + 32)*SEQ + t0 + cg],        &Vs[nxt + 2048 + wv*512]);
    }

    // S^T = K Q^T: A=K (m=t), B=Q (n=q). s[nq][nt]: lane q=col, t=nt*16+quad*4+r.
    f32x4 s[2][4] = {};
    #pragma unroll
    for (int kk = 0; kk < 2; kk++)
      #pragma unroll
      for (int nt = 0; nt < 4; nt++) {
        bf16x8 kf = *(const bf16x8*)&Ks[cur + (nt*16 + col)*64 + (kk ? ck1 : ck0)];
        #pragma unroll
        for (int nq = 0; nq < 2; nq++)
          s[nq][nt] = __builtin_amdgcn_mfma_f32_16x16x32_bf16(kf, qf[nq][kk], s[nq][nt], 0, 0, 0);
      }

    // p = exp2(s) (Q pre-scaled); pack in-register into 16x16x16 B-fragments (k=quad*4+j)
    s16x4 pfrag[2][4];
    #pragma unroll
    for (int nq = 0; nq < 2; nq++)
      #pragma unroll
      for (int nt = 0; nt < 4; nt++) {
        uint2 w2;
        w2.x = pack2bf(__builtin_exp2f(s[nq][nt][0]), __builtin_exp2f(s[nq][nt][1]));
        w2.y = pack2bf(__builtin_exp2f(s[nq][nt][2]), __builtin_exp2f(s[nq][nt][3]));
        __builtin_memcpy(&pfrag[nq][nt], &w2, 8);
      }

    // O^T += V^T P^T via 16x16x16 (V^T A-frag: m=d=mi*16+col, k=t=nt*16+quad*4+j -> b64)
    #pragma unroll
    for (int nt = 0; nt < 4; nt++) {
      #pragma unroll
      for (int mi = 0; mi < 4; mi++) {
        s16x4 vf = *(const s16x4*)&Vs[cur + (mi*16 + col)*64 + cv[nt]];
        #pragma unroll
        for (int nq = 0; nq < 2; nq++)
          o[nq][mi] = mfma16(vf, pfrag[nq][nt], o[nq][mi]);
      }
      #pragma unroll
      for (int nq = 0; nq < 2; nq++)
        rsacc[nq] = mfma16(ones16, pfrag[nq][nt], rsacc[nq]);
    }
  }

  // normalize and store O^T -> ao[q][h*64+d]
  #pragma unroll
  for (int nq = 0; nq < 2; nq++) {
    float inv = 1.0f / rsacc[nq][0];
    u16* aop = ao + (size_t)(b*SEQ + qt*128 + wv*32 + nq*16 + col)*HIDDEN + h*HD;
    #pragma unroll
    for (int mi = 0; mi < 4; mi++) {
      uint2 w2;
      w2.x = pack2bf(o[nq][mi][0]*inv, o[nq][mi][1]*inv);
      w2.y = pack2bf(o[nq][mi][2]*inv, o[nq][mi][3]*inv);
      *(uint2*)&aop[mi*16 + quad*4] = w2;
    }
  }
}

extern "C" void kernel_launch(void* const* d_in, const int* in_sizes, int n_in,
                              void* d_out, int out_size, void* d_ws, size_t ws_size,
                              hipStream_t stream) {
  const float* x  = (const float*)d_in[0];
  const float* Wq = (const float*)d_in[1];
  const float* bq = (const float*)d_in[2];
  const float* Wk = (const float*)d_in[3];
  const float* bk = (const float*)d_in[4];
  const float* Wv = (const float*)d_in[5];
  const float* bv = (const float*)d_in[6];
  const float* Wo = (const float*)d_in[7];
  const float* bo = (const float*)d_in[8];
  float* out = (float*)d_out;

  char* w = (char*)d_ws;
  u16* xb    = (u16*)w; w += (size_t)MTOT*HIDDEN*2;        // 8 MB
  u16* wtqkv = (u16*)w; w += (size_t)3*HIDDEN*HIDDEN*2;    // 6 MB
  u16* wto   = (u16*)w; w += (size_t)HIDDEN*HIDDEN*2;      // 2 MB
  u16* qkvb  = (u16*)w; w += (size_t)MTOT*3*HIDDEN*2;      // 24 MB
  u16* vtb   = (u16*)w; w += (size_t)BATCH*NH*HD*SEQ*2;    // 8 MB
  u16* aob   = (u16*)w; w += (size_t)MTOT*HIDDEN*2;        // 8 MB

  convert_x_kernel<<<(MTOT*HIDDEN)/1024, 256, 0, stream>>>(x, xb);
  transpose_w_kernel<<<dim3(32, 32, 4), 256, 0, stream>>>(Wq, Wk, Wv, Wo, wtqkv, wto);
  gemm_bt<1,128><<<dim3(32, 24), 256, 0, stream>>>(xb, wtqkv, bq, bk, bv, qkvb, nullptr, MTOT, 3*HIDDEN, HIDDEN);
  transpose_v_kernel<<<dim3(SEQ/32, 2, BATCH*NH), 256, 0, stream>>>(qkvb, vtb);
  attn_kernel<<<dim3(SEQ/128, BATCH*NH), 256, 0, stream>>>(qkvb, vtb, aob);
  gemm_bt<0,64><<<dim3(64, 8), 256, 0, stream>>>(aob, wto, bo, nullptr, nullptr, nullptr, out, MTOT, HIDDEN, HIDDEN);
}